// Round 19
// baseline (326.303 us; speedup 1.0000x reference)
//
#include <hip/hip_runtime.h>
#include <hip/hip_bf16.h>
#include <math.h>

#define B_ 4
#define N_ 1024
#define D_ 1024
#define H_ 16
#define DH_ 64
#define DM_ 4096
#define NT_ (B_*N_)
#define EPS_ 1e-5f
#define SCALE_ 0.125f
#define CEXP_ 0.1803368801111244f  /* 0.125 * log2(e) */

typedef unsigned short u16;
typedef short s16x8 __attribute__((ext_vector_type(8)));
typedef __bf16 y16x8 __attribute__((ext_vector_type(8)));
typedef float f32x4 __attribute__((ext_vector_type(4)));
typedef float f32x16 __attribute__((ext_vector_type(16)));

#define ZERO16 (f32x16){0.f,0.f,0.f,0.f,0.f,0.f,0.f,0.f,0.f,0.f,0.f,0.f,0.f,0.f,0.f,0.f}

__device__ __forceinline__ u16 f2bs(float f) {
  unsigned int u = __builtin_bit_cast(unsigned int, f);
  u += 0x7fffu + ((u >> 16) & 1u);
  return (u16)(u >> 16);
}

static __device__ __forceinline__ f32x4 MFMA(y16x8 a, y16x8 b, f32x4 c) {
  return __builtin_amdgcn_mfma_f32_16x16x32_bf16(a, b, c, 0, 0, 0);
}
static __device__ __forceinline__ f32x16 MFMA32(y16x8 a, y16x8 b, f32x16 c) {
  return __builtin_amdgcn_mfma_f32_32x32x16_bf16(a, b, c, 0, 0, 0);
}

static __device__ __forceinline__ unsigned cvtpk(float a, float b) {
  unsigned r;
  asm("v_cvt_pk_bf16_f32 %0, %1, %2" : "=v"(r) : "v"(a), "v"(b));
  return r;
}

static __device__ __forceinline__ void async16(void* lds, const void* g) {
  __builtin_amdgcn_global_load_lds(
      (const __attribute__((address_space(1))) unsigned int*)g,
      (__attribute__((address_space(3))) unsigned int*)lds, 16, 0, 0);
}

// ---- merged prep:
// [0,1024)      8 x DxD transpose (64k x 128n tiles, float4 reads)
// [1024,1536)   W1 transpose   | [1536,2048) W2 transpose
// [2048,6144)   encprep        | [6144,10240) ln1(+PE)
__global__ __launch_bounds__(256) void k_prep(
    const float* __restrict__ s0, const float* __restrict__ s1,
    const float* __restrict__ s2, const float* __restrict__ s3,
    const float* __restrict__ s4, const float* __restrict__ s5,
    const float* __restrict__ s6, const float* __restrict__ s7,
    u16* __restrict__ w8, const float* __restrict__ mW1,
    u16* __restrict__ w1T, const float* __restrict__ mW2,
    u16* __restrict__ w2T, const float* __restrict__ enc,
    const float* __restrict__ pe, u16* __restrict__ encpe,
    u16* __restrict__ encv,
    const float* __restrict__ xdec, const float* __restrict__ g1,
    const float* __restrict__ bta1, const float* __restrict__ pedec,
    u16* __restrict__ x2o, u16* __restrict__ qko) {
  __shared__ __align__(16) u16 tile[128][72];  // [n][k], 144B rows (16B-mult)
  __shared__ float red[8];
  const int gid = blockIdx.x;
  const int t = threadIdx.x;
  if (gid < 2048) {
    const float* W;
    u16* Wt;
    int K, Ncols, k0, n0;
    if (gid < 1024) {
      int z = gid >> 7, rem = gid & 127;
      W = z == 0 ? s0 : z == 1 ? s1 : z == 2 ? s2 : z == 3 ? s3
        : z == 4 ? s4 : z == 5 ? s5 : z == 6 ? s6 : s7;
      Wt = w8 + (size_t)z * D_ * D_;
      K = D_; Ncols = D_;
      k0 = (rem & 15) * 64; n0 = (rem >> 4) * 128;
    } else if (gid < 1536) {
      int rem = gid - 1024;
      W = mW1; Wt = w1T; K = D_; Ncols = DM_;
      k0 = (rem & 15) * 64; n0 = (rem >> 4) * 128;
    } else {
      int rem = gid - 1536;
      W = mW2; Wt = w2T; K = DM_; Ncols = D_;
      k0 = (rem & 63) * 64; n0 = (rem >> 6) * 128;
    }
    const int l32 = t & 31, rk = t >> 5;     // 512B contiguous per k-row
#pragma unroll
    for (int i = 0; i < 8; ++i) {
      int k = i * 8 + rk;
      float4 v = *(const float4*)(W + (size_t)(k0 + k) * Ncols + n0 + l32 * 4);
      tile[l32 * 4 + 0][k] = f2bs(v.x);
      tile[l32 * 4 + 1][k] = f2bs(v.y);
      tile[l32 * 4 + 2][k] = f2bs(v.z);
      tile[l32 * 4 + 3][k] = f2bs(v.w);
    }
    __syncthreads();
    const int nr = t >> 3, c = t & 7;        // 128B contiguous write per n-row
#pragma unroll
    for (int p = 0; p < 4; ++p) {
      int n = p * 32 + nr;
      *(s16x8*)(Wt + (size_t)(n0 + n) * K + k0 + c * 8) =
          *(const s16x8*)&tile[n][c * 8];
    }
  } else if (gid < 6144) {
    int i = (gid - 2048) * 256 + t;
    float4 e = ((const float4*)enc)[i];
    float4 p = ((const float4*)pe)[i];
    union { u16 u[4]; uint2 v; } a, b;
    a.u[0] = f2bs(e.x + p.x); a.u[1] = f2bs(e.y + p.y);
    a.u[2] = f2bs(e.z + p.z); a.u[3] = f2bs(e.w + p.w);
    b.u[0] = f2bs(e.x); b.u[1] = f2bs(e.y); b.u[2] = f2bs(e.z); b.u[3] = f2bs(e.w);
    ((uint2*)encpe)[i] = a.v;
    ((uint2*)encv)[i] = b.v;
  } else {
    // ln1: row = gid - 6144
    int row = gid - 6144;
    float4 v = ((const float4*)(xdec + (size_t)row * D_))[t];
    float s = v.x + v.y + v.z + v.w;
#pragma unroll
    for (int o = 1; o < 64; o <<= 1) s += __shfl_xor(s, o, 64);
    if ((t & 63) == 0) red[t >> 6] = s;
    __syncthreads();
    float mean = (red[0] + red[1] + red[2] + red[3]) * (1.0f / D_);
    float dx = v.x - mean, dy = v.y - mean, dz = v.z - mean, dw = v.w - mean;
    float s2 = dx * dx + dy * dy + dz * dz + dw * dw;
#pragma unroll
    for (int o = 1; o < 64; o <<= 1) s2 += __shfl_xor(s2, o, 64);
    if ((t & 63) == 0) red[4 + (t >> 6)] = s2;
    __syncthreads();
    float var = (red[4] + red[5] + red[6] + red[7]) * (1.0f / D_);
    float rstd = rsqrtf(var + EPS_);
    float4 gv = ((const float4*)g1)[t];
    float4 bv = ((const float4*)bta1)[t];
    float y0 = dx * rstd * gv.x + bv.x;
    float y1 = dy * rstd * gv.y + bv.y;
    float y2 = dz * rstd * gv.z + bv.z;
    float y3 = dw * rstd * gv.w + bv.w;
    union { u16 u[4]; uint2 v2; } o1;
    o1.u[0] = f2bs(y0); o1.u[1] = f2bs(y1); o1.u[2] = f2bs(y2); o1.u[3] = f2bs(y3);
    ((uint2*)(x2o + (size_t)row * D_))[t] = o1.v2;
    float4 pv = ((const float4*)(pedec + (size_t)row * D_))[t];
    union { u16 u[4]; uint2 v2; } o2;
    o2.u[0] = f2bs(y0 + pv.x); o2.u[1] = f2bs(y1 + pv.y);
    o2.u[2] = f2bs(y2 + pv.z); o2.u[3] = f2bs(y3 + pv.w);
    ((uint2*)(qko + (size_t)row * D_))[t] = o2.v2;
  }
}

// ---------------- LayerNorm (+optional PE add), bf16 outputs ----------------
__global__ __launch_bounds__(256) void k_ln(const float* __restrict__ x,
                                            const float* __restrict__ g,
                                            const float* __restrict__ bta,
                                            const float* __restrict__ pe,
                                            u16* __restrict__ x2o,
                                            u16* __restrict__ qko) {
  int row = blockIdx.x;
  int t = threadIdx.x;
  float4 v = ((const float4*)(x + (size_t)row * D_))[t];
  float s = v.x + v.y + v.z + v.w;
#pragma unroll
  for (int o = 1; o < 64; o <<= 1) s += __shfl_xor(s, o, 64);
  __shared__ float red[8];
  if ((t & 63) == 0) red[t >> 6] = s;
  __syncthreads();
  float mean = (red[0] + red[1] + red[2] + red[3]) * (1.0f / D_);
  float dx = v.x - mean, dy = v.y - mean, dz = v.z - mean, dw = v.w - mean;
  float s2 = dx * dx + dy * dy + dz * dz + dw * dw;
#pragma unroll
  for (int o = 1; o < 64; o <<= 1) s2 += __shfl_xor(s2, o, 64);
  if ((t & 63) == 0) red[4 + (t >> 6)] = s2;
  __syncthreads();
  float var = (red[4] + red[5] + red[6] + red[7]) * (1.0f / D_);
  float rstd = rsqrtf(var + EPS_);
  float4 gv = ((const float4*)g)[t];
  float4 bv = ((const float4*)bta)[t];
  float y0 = dx * rstd * gv.x + bv.x;
  float y1 = dy * rstd * gv.y + bv.y;
  float y2 = dz * rstd * gv.z + bv.z;
  float y3 = dw * rstd * gv.w + bv.w;
  union { u16 u[4]; uint2 v2; } o1;
  o1.u[0] = f2bs(y0); o1.u[1] = f2bs(y1); o1.u[2] = f2bs(y2); o1.u[3] = f2bs(y3);
  ((uint2*)(x2o + (size_t)row * D_))[t] = o1.v2;
  if (pe) {
    float4 pv = ((const float4*)(pe + (size_t)row * D_))[t];
    union { u16 u[4]; uint2 v2; } o2;
    o2.u[0] = f2bs(y0 + pv.x); o2.u[1] = f2bs(y1 + pv.y);
    o2.u[2] = f2bs(y2 + pv.z); o2.u[3] = f2bs(y3 + pv.w);
    ((uint2*)(qko + (size_t)row * D_))[t] = o2.v2;
  }
}

// ---- GEMM: A(M,K)bf16 @ Bt(N,K)^T + bias. 512 thr, 2-phase dbuf, XCD swizzle.
// BM=128: 8 waves x (64x32), acc[4][2]; BM=64: 8 waves x (32x32), acc[2][2]
template <int EPI, int BM>
__global__ __launch_bounds__(512) void k_gemm(const u16* __restrict__ A,
                                              const u16* __restrict__ Bt,
                                              const float* __restrict__ bias,
                                              const float* __restrict__ res,
                                              float* __restrict__ outf,
                                              u16* __restrict__ outb,
                                              int M, int Nn, int K, int ldo) {
  constexpr int BN = 128, BK = 64;
  constexpr int FM = BM / 32;
  __shared__ __align__(128) char smem[2][(BM + BN) * BK * 2];
  const int t = threadIdx.x;
  const int wave = t >> 6, lane = t & 63, lg = lane >> 4, lc = lane & 15;
  const int nwg = gridDim.x * gridDim.y;
  const int bid = blockIdx.y * gridDim.x + blockIdx.x;
  const int lb = (bid & 7) * (nwg >> 3) + (bid >> 3);
  const int bx = lb % gridDim.x, by = lb / gridDim.x;
  const int m0 = by * BM, n0 = bx * BN;
  const int wm = (wave >> 2) * (BM / 2), wn = (wave & 3) * 32;
  f32x4 acc[FM][2];
#pragma unroll
  for (int i = 0; i < FM; ++i)
#pragma unroll
    for (int j = 0; j < 2; ++j) acc[i][j] = (f32x4){0.f, 0.f, 0.f, 0.f};
  const char* Ag = (const char*)(A + (size_t)m0 * K);
  const char* Bg = (const char*)(Bt + (size_t)n0 * K);
  const int sr = t >> 3, sp = t & 7;

  auto stage = [&](int bufi, int kt) {
    char* sA = smem[bufi];
    char* sB = smem[bufi] + BM * BK * 2;
#pragma unroll
    for (int rr = 0; rr < BM / 64; ++rr) {
      int row = rr * 64 + sr;
      int c = sp ^ (row & 7);
      async16(sA + (size_t)row * 128 + sp * 16,
              Ag + ((size_t)row * K + kt + c * 8) * 2);
    }
#pragma unroll
    for (int rr = 0; rr < 2; ++rr) {
      int row = rr * 64 + sr;
      int c = sp ^ (row & 7);
      async16(sB + (size_t)row * 128 + sp * 16,
              Bg + ((size_t)row * K + kt + c * 8) * 2);
    }
  };
  auto compute = [&](int bufi) {
    const char* sA = smem[bufi];
    const char* sB = smem[bufi] + BM * BK * 2;
#pragma unroll
    for (int ks = 0; ks < 2; ++ks) {
      y16x8 af[FM], bfr[2];
#pragma unroll
      for (int fm = 0; fm < FM; ++fm) {
        int R = wm + fm * 16 + lc;
        int pc = (ks * 4 + lg) ^ (R & 7);
        af[fm] = *(const y16x8*)(sA + (size_t)R * 128 + pc * 16);
      }
#pragma unroll
      for (int fn = 0; fn < 2; ++fn) {
        int R = wn + fn * 16 + lc;
        int pc = (ks * 4 + lg) ^ (R & 7);
        bfr[fn] = *(const y16x8*)(sB + (size_t)R * 128 + pc * 16);
      }
#pragma unroll
      for (int fm = 0; fm < FM; ++fm)
#pragma unroll
        for (int fn = 0; fn < 2; ++fn)
          acc[fm][fn] = MFMA(af[fm], bfr[fn], acc[fm][fn]);
    }
  };

  stage(0, 0);
  __syncthreads();
  int cur = 0;
  for (int kt = BK; kt < K; kt += BK) {
    stage(cur ^ 1, kt);
    compute(cur);
    __syncthreads();
    cur ^= 1;
  }
  compute(cur);

#pragma unroll
  for (int fm = 0; fm < FM; ++fm)
#pragma unroll
    for (int fn = 0; fn < 2; ++fn)
#pragma unroll
      for (int j = 0; j < 4; ++j) {
        int row = m0 + wm + fm * 16 + lg * 4 + j;
        int col = n0 + wn + fn * 16 + lc;
        float vv = acc[fm][fn][j] + bias[col];
        size_t idx = (size_t)row * ldo + col;
        if constexpr (EPI == 0) {
          outb[idx] = f2bs(vv);
        } else if constexpr (EPI == 1) {
          outf[idx] = vv + res[idx];
        } else {
          float gx = 0.5f * vv * (1.0f + erff(vv * 0.70710678118f));
          outb[idx] = f2bs(gx);
        }
      }
}

// ------- grouped 5-way projection GEMM: grid (8,32,5), 512 thr dbuf.
__global__ __launch_bounds__(512) void k_gemmG(
    const u16* __restrict__ A0, const u16* __restrict__ A1,
    const u16* __restrict__ A2, const u16* __restrict__ A3,
    const u16* __restrict__ A4, const u16* __restrict__ W0,
    const u16* __restrict__ W1, const u16* __restrict__ W2,
    const u16* __restrict__ W3, const u16* __restrict__ W4,
    const float* __restrict__ b0, const float* __restrict__ b1,
    const float* __restrict__ b2, const float* __restrict__ b3,
    const float* __restrict__ b4, u16* __restrict__ qk1,
    u16* __restrict__ vt1, u16* __restrict__ qk2, u16* __restrict__ vt2) {
  constexpr int BM = 128, BN = 128, BK = 64, K = D_;
  __shared__ __align__(128) char smem[2][(BM + BN) * BK * 2];
  const int z = blockIdx.z;
  const u16* A = z == 0 ? A0 : z == 1 ? A1 : z == 2 ? A2 : z == 3 ? A3 : A4;
  const u16* Bt = z == 0 ? W0 : z == 1 ? W1 : z == 2 ? W2 : z == 3 ? W3 : W4;
  const float* bias = z == 0 ? b0 : z == 1 ? b1 : z == 2 ? b2 : z == 3 ? b3 : b4;
  const int t = threadIdx.x;
  const int wave = t >> 6, lane = t & 63, lg = lane >> 4, lc = lane & 15;
  const int nwg = gridDim.x * gridDim.y;
  const int bid = blockIdx.y * gridDim.x + blockIdx.x;
  const int lb = (bid & 7) * (nwg >> 3) + (bid >> 3);
  const int bx = lb % gridDim.x, by = lb / gridDim.x;
  const int m0 = by * BM, n0 = bx * BN;
  const int wm = (wave >> 2) * 64, wn = (wave & 3) * 32;
  f32x4 acc[4][2];
#pragma unroll
  for (int i = 0; i < 4; ++i)
#pragma unroll
    for (int j = 0; j < 2; ++j) acc[i][j] = (f32x4){0.f, 0.f, 0.f, 0.f};
  const char* Ag = (const char*)(A + (size_t)m0 * K);
  const char* Bg = (const char*)(Bt + (size_t)n0 * K);
  const int sr = t >> 3, sp = t & 7;

  auto stage = [&](int bufi, int kt) {
    char* sA = smem[bufi];
    char* sB = smem[bufi] + BM * BK * 2;
#pragma unroll
    for (int rr = 0; rr < 2; ++rr) {
      int row = rr * 64 + sr;
      int c = sp ^ (row & 7);
      async16(sA + (size_t)row * 128 + sp * 16,
              Ag + ((size_t)row * K + kt + c * 8) * 2);
      async16(sB + (size_t)row * 128 + sp * 16,
              Bg + ((size_t)row * K + kt + c * 8) * 2);
    }
  };
  auto compute = [&](int bufi) {
    const char* sA = smem[bufi];
    const char* sB = smem[bufi] + BM * BK * 2;
#pragma unroll
    for (int ks = 0; ks < 2; ++ks) {
      y16x8 af[4], bfr[2];
#pragma unroll
      for (int fm = 0; fm < 4; ++fm) {
        int R = wm + fm * 16 + lc;
        int pc = (ks * 4 + lg) ^ (R & 7);
        af[fm] = *(const y16x8*)(sA + (size_t)R * 128 + pc * 16);
      }
#pragma unroll
      for (int fn = 0; fn < 2; ++fn) {
        int R = wn + fn * 16 + lc;
        int pc = (ks * 4 + lg) ^ (R & 7);
        bfr[fn] = *(const y16x8*)(sB + (size_t)R * 128 + pc * 16);
      }
#pragma unroll
      for (int fm = 0; fm < 4; ++fm)
#pragma unroll
        for (int fn = 0; fn < 2; ++fn)
          acc[fm][fn] = MFMA(af[fm], bfr[fn], acc[fm][fn]);
    }
  };

  stage(0, 0);
  __syncthreads();
  int cur = 0;
  for (int kt = BK; kt < K; kt += BK) {
    stage(cur ^ 1, kt);
    compute(cur);
    __syncthreads();
    cur ^= 1;
  }
  compute(cur);

  const bool isV = (z == 2) || (z == 4);
  if (!isV) {
    u16* outqk = (z == 3) ? qk2 : qk1;
    const int coff = (z == 1 || z == 3) ? D_ : 0;
#pragma unroll
    for (int fm = 0; fm < 4; ++fm)
#pragma unroll
      for (int fn = 0; fn < 2; ++fn)
#pragma unroll
        for (int j = 0; j < 4; ++j) {
          int row = m0 + wm + fm * 16 + lg * 4 + j;
          int col = n0 + wn + fn * 16 + lc;
          outqk[(size_t)row * (2 * D_) + coff + col] =
              f2bs(acc[fm][fn][j] + bias[col]);
        }
  } else {
    u16* outvt = (z == 2) ? vt1 : vt2;
#pragma unroll
    for (int fm = 0; fm < 4; ++fm)
#pragma unroll
      for (int fn = 0; fn < 2; ++fn) {
        int row0 = m0 + wm + fm * 16 + lg * 4;
        int col = n0 + wn + fn * 16 + lc;
        int bb = row0 >> 10, nn = row0 & (N_ - 1);
        int h = col >> 6, dh = col & 63;
        float bcol = bias[col];
        union { u16 u[4]; uint2 v; } pk;
#pragma unroll
        for (int j = 0; j < 4; ++j) pk.u[j] = f2bs(acc[fm][fn][j] + bcol);
        *(uint2*)&outvt[(((size_t)bb * H_ + h) * DH_ + dh) * N_ + nn] = pk.v;
      }
  }
}

// -------- flash attention, swapped-QK 32x32 MFMA, in-register softmax -------
// 128-key staged tile, two 64-key sub-passes; T14 reg prefetch; T13 defer-max;
// T5 setprio.
__global__ __launch_bounds__(256) void k_attn(const u16* __restrict__ q, int qs,
                                              const u16* __restrict__ k, int ks2,
                                              const u16* __restrict__ vt,
                                              u16* __restrict__ out) {
  __shared__ __align__(16) u16 Kl[128][64];
  __shared__ __align__(16) u16 Vl[64][128];
  __shared__ __align__(16) u16 Ol[4][32][72];
  const int lb = blockIdx.x;
  const int bh = (lb & 7) | ((lb >> 6) << 3);
  const int qb = (lb >> 3) & 7;
  const int b = bh >> 4, h = bh & 15;
  const int t = threadIdx.x, wave = t >> 6, lane = t & 63;
  const int ql = lane & 31, hi = lane >> 5;
  const int q0 = qb * 128 + wave * 32;
  const u16* qp = q + ((size_t)b * N_ + q0) * qs + h * DH_;
  const u16* kp = k + (size_t)b * N_ * ks2 + h * DH_;
  const u16* vp = vt + ((size_t)bh * DH_) * N_;

  y16x8 aq[4];
#pragma unroll
  for (int s = 0; s < 4; ++s)
    aq[s] = *(const y16x8*)(qp + (size_t)ql * qs + s * 16 + hi * 8);

  f32x16 o0 = ZERO16, o1 = ZERO16;
  float m_r = -1e30f, l_r = 0.f;

  const int kr = t >> 3, kc = t & 7;
  const int vr = t >> 4, vc = t & 15;
  s16x8 kreg[4], vreg[4];
#pragma unroll
  for (int rr = 0; rr < 4; ++rr) {
    kreg[rr] = *(const s16x8*)(kp + (size_t)(rr * 32 + kr) * ks2 + kc * 8);
    vreg[rr] = *(const s16x8*)(vp + (size_t)(rr * 16 + vr) * N_ + vc * 8);
  }

  for (int kt = 0; kt < N_; kt += 128) {
    __syncthreads();
#pragma unroll
    for (int rr = 0; rr < 4; ++rr) {
      int krow = rr * 32 + kr;
      *(s16x8*)&Kl[krow][(kc ^ (krow & 7)) * 8] = kreg[rr];
      int vrow = rr * 16 + vr;
      *(s16x8*)&Vl[vrow][(vc ^ (vrow & 15)) * 8] = vreg[rr];
    }
    __syncthreads();
    if (kt + 128 < N_) {
#pragma unroll
      for (int rr = 0; rr < 4; ++rr) {
        kreg[rr] = *(const s16x8*)(kp + (size_t)(kt + 128 + rr * 32 + kr) * ks2 + kc * 8);
        vreg[rr] = *(const s16x8*)(vp + (size_t)(rr * 16 + vr) * N_ + kt + 128 + vc * 8);
      }
    }

#pragma unroll
    for (int sub = 0; sub < 2; ++sub) {
      f32x16 st0 = ZERO16, st1 = ZERO16;
      __builtin_amdgcn_s_setprio(1);
#pragma unroll
      for (int s = 0; s < 4; ++s) {
        int pc0 = ((s * 2 + hi) ^ (ql & 7)) * 8;
        y16x8 ak0 = *(const y16x8*)&Kl[sub * 64 + ql][pc0];
        y16x8 ak1 = *(const y16x8*)&Kl[sub * 64 + 32 + ql][pc0];
        st0 = MFMA32(ak0, aq[s], st0);
        st1 = MFMA32(ak1, aq[s], st1);
      }
      __builtin_amdgcn_s_setprio(0);

      float mx = st0[0];
#pragma unroll
      for (int r = 1; r < 16; ++r) mx = fmaxf(mx, st0[r]);
#pragma unroll
      for (int r = 0; r < 16; ++r) mx = fmaxf(mx, st1[r]);
      mx = fmaxf(mx, __shfl_xor(mx, 32, 64));
      if (!__all(mx - m_r <= 32.f)) {
        float mn = fmaxf(m_r, mx);
        float corr = exp2f((m_r - mn) * CEXP_);
        l_r *= corr;
        o0 = o0 * corr;
        o1 = o1 * corr;
        m_r = mn;
      }
      float ps = 0.f;
#pragma unroll
      for (int r = 0; r < 16; ++r) {
        float e = exp2f((st0[r] - m_r) * CEXP_); st0[r] = e; ps += e;
      }
#pragma unroll
      for (int r = 0; r < 16; ++r) {
        float e = exp2f((st1[r] - m_r) * CEXP_); st1[r] = e; ps += e;
      }
      ps += __shfl_xor(ps, 32, 64);
      l_r += ps;

      __builtin_amdgcn_s_setprio(1);
#pragma unroll
      for (int ks = 0; ks < 4; ++ks) {
        unsigned A0, A1, B0, B1;
        if (ks < 2) {
          const int il = ks * 8;
          A0 = cvtpk(st0[il + 0], st0[il + 1]);
          A1 = cvtpk(st0[il + 2], st0[il + 3]);
          B0 = cvtpk(st0[il + 4], st0[il + 5]);
          B1 = cvtpk(st0[il + 6], st0[il + 7]);
        } else {
          const int il = (ks - 2) * 8;
          A0 = cvtpk(st1[il + 0], st1[il + 1]);
          A1 = cvtpk(st1[il + 2], st1[il + 3]);
          B0 = cvtpk(st1[il + 4], st1[il + 5]);
          B1 = cvtpk(st1[il + 6], st1[il + 7]);
        }
        asm("v_permlane32_swap_b32 %0, %1" : "+v"(A0), "+v"(B0));
        asm("v_permlane32_swap_b32 %0, %1" : "+v"(A1), "+v"(B1));
        union { unsigned w[4]; y16x8 v; } fr;
        fr.w[0] = A0; fr.w[1] = A1; fr.w[2] = B0; fr.w[3] = B1;
        int ch0 = (sub * 8 + ks * 2 + hi) ^ (ql & 15);
        int ch1 = (sub * 8 + ks * 2 + hi) ^ ((32 + ql) & 15);
        y16x8 bv0 = *(const y16x8*)&Vl[ql][ch0 * 8];
        y16x8 bv1 = *(const y16x8*)&Vl[32 + ql][ch1 * 8];
        o0 = MFMA32(bv0, fr.v, o0);
        o1 = MFMA32(bv1, fr.v, o1);
      }
      __builtin_amdgcn_s_setprio(0);
    }
  }

  float rl = 1.f / l_r;
#pragma unroll
  for (int rq = 0; rq < 4; ++rq)
#pragma unroll
    for (int e = 0; e < 4; e += 2) {
      *(unsigned*)&Ol[wave][ql][8 * rq + 4 * hi + e] =
          cvtpk(o0[rq * 4 + e] * rl, o0[rq * 4 + e + 1] * rl);
      *(unsigned*)&Ol[wave][ql][32 + 8 * rq + 4 * hi + e] =
          cvtpk(o1[rq * 4 + e] * rl, o1[rq * 4 + e + 1] * rl);
    }
#pragma unroll
  for (int pp = 0; pp < 4; ++pp) {
    int row = pp * 8 + (lane >> 3);
    s16x8 vv = *(const s16x8*)&Ol[wave][row][(lane & 7) * 8];
    *(s16x8*)(out + ((size_t)b * N_ + q0 + row) * D_ + h * DH_ + (lane & 7) * 8) = vv;
  }
}

extern "C" void kernel_launch(void* const* d_in, const int* in_sizes, int n_in,
                              void* d_out, int out_size, void* d_ws, size_t ws_size,
                              hipStream_t stream) {
  const float* tokens_enc = (const float*)d_in[0];
  const float* tokens_dec = (const float*)d_in[1];
  const float* PE_enc = (const float*)d_in[2];
  const float* PE_dec = (const float*)d_in[3];
  const float* sa_Wq = (const float*)d_in[4];  const float* sa_bq = (const float*)d_in[5];
  const float* sa_Wk = (const float*)d_in[6];  const float* sa_bk = (const float*)d_in[7];
  const float* sa_Wv = (const float*)d_in[8];  const float* sa_bv = (const float*)d_in[9];
  const float* sa_Wp = (const float*)d_in[10]; const float* sa_bp = (const float*)d_in[11];
  const float* ca_Wq = (const float*)d_in[12]; const float* ca_bq = (const float*)d_in[13];
  const float* ca_Wk = (const float*)d_in[14]; const float* ca_bk = (const float*)d_in[15];
  const float* ca_Wv = (const float*)d_in[16]; const float* ca_bv = (const float*)d_in[17];
  const float* ca_Wp = (const float*)d_in[18]; const float* ca_bp = (const float*)d_in[19];
  const float* mlp_W1 = (const float*)d_in[20]; const float* mlp_b1 = (const float*)d_in[21];
  const float* mlp_W2 = (const float*)d_in[22]; const float* mlp_b2 = (const float*)d_in[23];
  const float* ln1_g = (const float*)d_in[24]; const float* ln1_b = (const float*)d_in[25];
  const float* ln2_g = (const float*)d_in[26]; const float* ln2_b = (const float*)d_in[27];
  const float* ln3_g = (const float*)d_in[28]; const float* ln3_b = (const float*)d_in[29];

  char* wsp = (char*)d_ws;
  size_t off = 0;
  auto alloc = [&](size_t bytes) -> char* {
    char* p = wsp + off;
    off += (bytes + 255) & ~(size_t)255;
    return p;
  };
  u16* w8   = (u16*)alloc((size_t)8 * D_ * D_ * 2);
  u16* w1T  = (u16*)alloc((size_t)DM_ * D_ * 2);
  u16* w2T  = (u16*)alloc((size_t)D_ * DM_ * 2);
  u16* encpe = (u16*)alloc((size_t)NT_ * D_ * 2);
  u16* encv  = (u16*)alloc((size_t)NT_ * D_ * 2);
  u16* x2b = (u16*)alloc((size_t)NT_ * D_ * 2);
  u16* qkb = (u16*)alloc((size_t)NT_ * D_ * 2);
  u16* qkm = (u16*)alloc((size_t)NT_ * 2 * D_ * 2);
  u16* qkm2 = (u16*)alloc((size_t)NT_ * 2 * D_ * 2);
  u16* vtb = (u16*)alloc((size_t)NT_ * D_ * 2);
  u16* vtb2 = (u16*)alloc((size_t)NT_ * D_ * 2);
  u16* attb = (u16*)alloc((size_t)NT_ * D_ * 2);
  float* dec1 = (float*)alloc((size_t)NT_ * D_ * 4);
  float* dec2 = (float*)alloc((size_t)NT_ * D_ * 4);
  u16* hb = (u16*)alloc((size_t)NT_ * DM_ * 2);

  const size_t DD = (size_t)D_ * D_;
  u16* wqT  = w8;
  u16* wkT  = w8 + 1 * DD;
  u16* wvT  = w8 + 2 * DD;
  u16* wpT  = w8 + 3 * DD;
  u16* cwqT = w8 + 4 * DD;
  u16* cwkT = w8 + 5 * DD;
  u16* cwvT = w8 + 6 * DD;
  u16* cwpT = w8 + 7 * DD;

  // ---- prep (merged, incl. ln1) ----
  k_prep<<<dim3(10240), 256, 0, stream>>>(sa_Wq, sa_Wk, sa_Wv, sa_Wp,
                                          ca_Wq, ca_Wk, ca_Wv, ca_Wp, w8,
                                          mlp_W1, w1T, mlp_W2, w2T,
                                          tokens_enc, PE_enc, encpe, encv,
                                          tokens_dec, ln1_g, ln1_b, PE_dec,
                                          x2b, qkb);

  // ---- self-attention (+ CA K/V precompute) ----
  k_gemmG<<<dim3(8, 32, 5), 512, 0, stream>>>(
      qkb, qkb, x2b, encpe, encv, wqT, wkT, wvT, cwkT, cwvT,
      sa_bq, sa_bk, sa_bv, ca_bk, ca_bv, qkm, vtb, qkm2, vtb2);
  k_attn<<<dim3(512), 256, 0, stream>>>(qkm, 2 * D_, qkm + D_, 2 * D_, vtb, attb);
  k_gemm<1, 64><<<dim3(8, 64), 512, 0, stream>>>(attb, wpT, sa_bp, tokens_dec,
                                                 dec1, nullptr, NT_, D_, D_, D_);

  // ---- cross-attention ----
  k_ln<<<dim3(NT_), 256, 0, stream>>>(dec1, ln2_g, ln2_b, PE_dec, x2b, qkb);
  k_gemm<0, 64><<<dim3(8, 64), 512, 0, stream>>>(qkb, cwqT, ca_bq, nullptr,
                                                 nullptr, qkm2, NT_, D_, D_, 2 * D_);
  k_attn<<<dim3(512), 256, 0, stream>>>(qkm2, 2 * D_, qkm2 + D_, 2 * D_, vtb2, attb);
  k_gemm<1, 64><<<dim3(8, 64), 512, 0, stream>>>(attb, cwpT, ca_bp, dec1,
                                                 dec2, nullptr, NT_, D_, D_, D_);

  // ---- feed-forward ----
  k_ln<<<dim3(NT_), 256, 0, stream>>>(dec2, ln3_g, ln3_b, nullptr, x2b, nullptr);
  k_gemm<2, 128><<<dim3(32, 32), 512, 0, stream>>>(x2b, w1T, mlp_b1, nullptr,
                                                   nullptr, hb, NT_, DM_, D_, DM_);
  k_gemm<1, 64><<<dim3(8, 64), 512, 0, stream>>>(hb, w2T, mlp_b2, dec2,
                                                 (float*)d_out, nullptr, NT_, D_, DM_, D_);
}

// Round 20
// 325.633 us; speedup vs baseline: 1.0021x; 1.0021x over previous
//
#include <hip/hip_runtime.h>
#include <hip/hip_bf16.h>
#include <math.h>

#define B_ 4
#define N_ 1024
#define D_ 1024
#define H_ 16
#define DH_ 64
#define DM_ 4096
#define NT_ (B_*N_)
#define EPS_ 1e-5f
#define SCALE_ 0.125f
#define CEXP_ 0.1803368801111244f  /* 0.125 * log2(e) */

typedef unsigned short u16;
typedef short s16x8 __attribute__((ext_vector_type(8)));
typedef __bf16 y16x8 __attribute__((ext_vector_type(8)));
typedef float f32x4 __attribute__((ext_vector_type(4)));
typedef float f32x16 __attribute__((ext_vector_type(16)));

#define ZERO16 (f32x16){0.f,0.f,0.f,0.f,0.f,0.f,0.f,0.f,0.f,0.f,0.f,0.f,0.f,0.f,0.f,0.f}

__device__ __forceinline__ u16 f2bs(float f) {
  unsigned int u = __builtin_bit_cast(unsigned int, f);
  u += 0x7fffu + ((u >> 16) & 1u);
  return (u16)(u >> 16);
}

static __device__ __forceinline__ f32x4 MFMA(y16x8 a, y16x8 b, f32x4 c) {
  return __builtin_amdgcn_mfma_f32_16x16x32_bf16(a, b, c, 0, 0, 0);
}
static __device__ __forceinline__ f32x16 MFMA32(y16x8 a, y16x8 b, f32x16 c) {
  return __builtin_amdgcn_mfma_f32_32x32x16_bf16(a, b, c, 0, 0, 0);
}

static __device__ __forceinline__ unsigned cvtpk(float a, float b) {
  unsigned r;
  asm("v_cvt_pk_bf16_f32 %0, %1, %2" : "=v"(r) : "v"(a), "v"(b));
  return r;
}

static __device__ __forceinline__ void async16(void* lds, const void* g) {
  __builtin_amdgcn_global_load_lds(
      (const __attribute__((address_space(1))) unsigned int*)g,
      (__attribute__((address_space(3))) unsigned int*)lds, 16, 0, 0);
}

// ---- merged prep:
// [0,1024)     8 x DxD transpose (64k x 128n tiles, float4 reads)
// [1024,5120)  encprep         | [5120,9216) ln1(+PE)
__global__ __launch_bounds__(256) void k_prep(
    const float* __restrict__ s0, const float* __restrict__ s1,
    const float* __restrict__ s2, const float* __restrict__ s3,
    const float* __restrict__ s4, const float* __restrict__ s5,
    const float* __restrict__ s6, const float* __restrict__ s7,
    u16* __restrict__ w8, const float* __restrict__ enc,
    const float* __restrict__ pe, u16* __restrict__ encpe,
    u16* __restrict__ encv,
    const float* __restrict__ xdec, const float* __restrict__ g1,
    const float* __restrict__ bta1, const float* __restrict__ pedec,
    u16* __restrict__ x2o, u16* __restrict__ qko) {
  __shared__ __align__(16) u16 tile[128][72];
  __shared__ float red[8];
  const int gid = blockIdx.x;
  const int t = threadIdx.x;
  if (gid < 1024) {
    int z = gid >> 7, rem = gid & 127;
    const float* W = z == 0 ? s0 : z == 1 ? s1 : z == 2 ? s2 : z == 3 ? s3
                   : z == 4 ? s4 : z == 5 ? s5 : z == 6 ? s6 : s7;
    u16* Wt = w8 + (size_t)z * D_ * D_;
    int k0 = (rem & 15) * 64, n0 = (rem >> 4) * 128;
    const int l32 = t & 31, rk = t >> 5;
#pragma unroll
    for (int i = 0; i < 8; ++i) {
      int k = i * 8 + rk;
      float4 v = *(const float4*)(W + (size_t)(k0 + k) * D_ + n0 + l32 * 4);
      tile[l32 * 4 + 0][k] = f2bs(v.x);
      tile[l32 * 4 + 1][k] = f2bs(v.y);
      tile[l32 * 4 + 2][k] = f2bs(v.z);
      tile[l32 * 4 + 3][k] = f2bs(v.w);
    }
    __syncthreads();
    const int nr = t >> 3, c = t & 7;
#pragma unroll
    for (int p = 0; p < 4; ++p) {
      int n = p * 32 + nr;
      *(s16x8*)(Wt + (size_t)(n0 + n) * D_ + k0 + c * 8) =
          *(const s16x8*)&tile[n][c * 8];
    }
  } else if (gid < 5120) {
    int i = (gid - 1024) * 256 + t;
    float4 e = ((const float4*)enc)[i];
    float4 p = ((const float4*)pe)[i];
    union { u16 u[4]; uint2 v; } a, b;
    a.u[0] = f2bs(e.x + p.x); a.u[1] = f2bs(e.y + p.y);
    a.u[2] = f2bs(e.z + p.z); a.u[3] = f2bs(e.w + p.w);
    b.u[0] = f2bs(e.x); b.u[1] = f2bs(e.y); b.u[2] = f2bs(e.z); b.u[3] = f2bs(e.w);
    ((uint2*)encpe)[i] = a.v;
    ((uint2*)encv)[i] = b.v;
  } else {
    int row = gid - 5120;
    float4 v = ((const float4*)(xdec + (size_t)row * D_))[t];
    float s = v.x + v.y + v.z + v.w;
#pragma unroll
    for (int o = 1; o < 64; o <<= 1) s += __shfl_xor(s, o, 64);
    if ((t & 63) == 0) red[t >> 6] = s;
    __syncthreads();
    float mean = (red[0] + red[1] + red[2] + red[3]) * (1.0f / D_);
    float dx = v.x - mean, dy = v.y - mean, dz = v.z - mean, dw = v.w - mean;
    float s2 = dx * dx + dy * dy + dz * dz + dw * dw;
#pragma unroll
    for (int o = 1; o < 64; o <<= 1) s2 += __shfl_xor(s2, o, 64);
    if ((t & 63) == 0) red[4 + (t >> 6)] = s2;
    __syncthreads();
    float var = (red[4] + red[5] + red[6] + red[7]) * (1.0f / D_);
    float rstd = rsqrtf(var + EPS_);
    float4 gv = ((const float4*)g1)[t];
    float4 bv = ((const float4*)bta1)[t];
    float y0 = dx * rstd * gv.x + bv.x;
    float y1 = dy * rstd * gv.y + bv.y;
    float y2 = dz * rstd * gv.z + bv.z;
    float y3 = dw * rstd * gv.w + bv.w;
    union { u16 u[4]; uint2 v2; } o1;
    o1.u[0] = f2bs(y0); o1.u[1] = f2bs(y1); o1.u[2] = f2bs(y2); o1.u[3] = f2bs(y3);
    ((uint2*)(x2o + (size_t)row * D_))[t] = o1.v2;
    float4 pv = ((const float4*)(pedec + (size_t)row * D_))[t];
    union { u16 u[4]; uint2 v2; } o2;
    o2.u[0] = f2bs(y0 + pv.x); o2.u[1] = f2bs(y1 + pv.y);
    o2.u[2] = f2bs(y2 + pv.z); o2.u[3] = f2bs(y3 + pv.w);
    ((uint2*)(qko + (size_t)row * D_))[t] = o2.v2;
  }
}

// ---------------- LayerNorm (+optional PE add), bf16 outputs ----------------
__global__ __launch_bounds__(256) void k_ln(const float* __restrict__ x,
                                            const float* __restrict__ g,
                                            const float* __restrict__ bta,
                                            const float* __restrict__ pe,
                                            u16* __restrict__ x2o,
                                            u16* __restrict__ qko) {
  int row = blockIdx.x;
  int t = threadIdx.x;
  float4 v = ((const float4*)(x + (size_t)row * D_))[t];
  float s = v.x + v.y + v.z + v.w;
#pragma unroll
  for (int o = 1; o < 64; o <<= 1) s += __shfl_xor(s, o, 64);
  __shared__ float red[8];
  if ((t & 63) == 0) red[t >> 6] = s;
  __syncthreads();
  float mean = (red[0] + red[1] + red[2] + red[3]) * (1.0f / D_);
  float dx = v.x - mean, dy = v.y - mean, dz = v.z - mean, dw = v.w - mean;
  float s2 = dx * dx + dy * dy + dz * dz + dw * dw;
#pragma unroll
  for (int o = 1; o < 64; o <<= 1) s2 += __shfl_xor(s2, o, 64);
  if ((t & 63) == 0) red[4 + (t >> 6)] = s2;
  __syncthreads();
  float var = (red[4] + red[5] + red[6] + red[7]) * (1.0f / D_);
  float rstd = rsqrtf(var + EPS_);
  float4 gv = ((const float4*)g)[t];
  float4 bv = ((const float4*)bta)[t];
  float y0 = dx * rstd * gv.x + bv.x;
  float y1 = dy * rstd * gv.y + bv.y;
  float y2 = dz * rstd * gv.z + bv.z;
  float y3 = dw * rstd * gv.w + bv.w;
  union { u16 u[4]; uint2 v2; } o1;
  o1.u[0] = f2bs(y0); o1.u[1] = f2bs(y1); o1.u[2] = f2bs(y2); o1.u[3] = f2bs(y3);
  ((uint2*)(x2o + (size_t)row * D_))[t] = o1.v2;
  if (pe) {
    float4 pv = ((const float4*)(pe + (size_t)row * D_))[t];
    union { u16 u[4]; uint2 v2; } o2;
    o2.u[0] = f2bs(y0 + pv.x); o2.u[1] = f2bs(y1 + pv.y);
    o2.u[2] = f2bs(y2 + pv.z); o2.u[3] = f2bs(y3 + pv.w);
    ((uint2*)(qko + (size_t)row * D_))[t] = o2.v2;
  }
}

// ---- GEMM: A(M,K)bf16 @ Bt(N,K)^T + bias. 512 thr, 2-phase dbuf, XCD swizzle.
template <int EPI, int BM>
__global__ __launch_bounds__(512) void k_gemm(const u16* __restrict__ A,
                                              const u16* __restrict__ Bt,
                                              const float* __restrict__ bias,
                                              const float* __restrict__ res,
                                              float* __restrict__ outf,
                                              u16* __restrict__ outb,
                                              int M, int Nn, int K, int ldo) {
  constexpr int BN = 128, BK = 64;
  constexpr int FM = BM / 32;
  __shared__ __align__(128) char smem[2][(BM + BN) * BK * 2];
  const int t = threadIdx.x;
  const int wave = t >> 6, lane = t & 63, lg = lane >> 4, lc = lane & 15;
  const int nwg = gridDim.x * gridDim.y;
  const int bid = blockIdx.y * gridDim.x + blockIdx.x;
  const int lb = (bid & 7) * (nwg >> 3) + (bid >> 3);
  const int bx = lb % gridDim.x, by = lb / gridDim.x;
  const int m0 = by * BM, n0 = bx * BN;
  const int wm = (wave >> 2) * (BM / 2), wn = (wave & 3) * 32;
  f32x4 acc[FM][2];
#pragma unroll
  for (int i = 0; i < FM; ++i)
#pragma unroll
    for (int j = 0; j < 2; ++j) acc[i][j] = (f32x4){0.f, 0.f, 0.f, 0.f};
  const char* Ag = (const char*)(A + (size_t)m0 * K);
  const char* Bg = (const char*)(Bt + (size_t)n0 * K);
  const int sr = t >> 3, sp = t & 7;

  auto stage = [&](int bufi, int kt) {
    char* sA = smem[bufi];
    char* sB = smem[bufi] + BM * BK * 2;
#pragma unroll
    for (int rr = 0; rr < BM / 64; ++rr) {
      int row = rr * 64 + sr;
      int c = sp ^ (row & 7);
      async16(sA + (size_t)row * 128 + sp * 16,
              Ag + ((size_t)row * K + kt + c * 8) * 2);
    }
#pragma unroll
    for (int rr = 0; rr < 2; ++rr) {
      int row = rr * 64 + sr;
      int c = sp ^ (row & 7);
      async16(sB + (size_t)row * 128 + sp * 16,
              Bg + ((size_t)row * K + kt + c * 8) * 2);
    }
  };
  auto compute = [&](int bufi) {
    const char* sA = smem[bufi];
    const char* sB = smem[bufi] + BM * BK * 2;
#pragma unroll
    for (int ks = 0; ks < 2; ++ks) {
      y16x8 af[FM], bfr[2];
#pragma unroll
      for (int fm = 0; fm < FM; ++fm) {
        int R = wm + fm * 16 + lc;
        int pc = (ks * 4 + lg) ^ (R & 7);
        af[fm] = *(const y16x8*)(sA + (size_t)R * 128 + pc * 16);
      }
#pragma unroll
      for (int fn = 0; fn < 2; ++fn) {
        int R = wn + fn * 16 + lc;
        int pc = (ks * 4 + lg) ^ (R & 7);
        bfr[fn] = *(const y16x8*)(sB + (size_t)R * 128 + pc * 16);
      }
#pragma unroll
      for (int fm = 0; fm < FM; ++fm)
#pragma unroll
        for (int fn = 0; fn < 2; ++fn)
          acc[fm][fn] = MFMA(af[fm], bfr[fn], acc[fm][fn]);
    }
  };

  stage(0, 0);
  __syncthreads();
  int cur = 0;
  for (int kt = BK; kt < K; kt += BK) {
    stage(cur ^ 1, kt);
    compute(cur);
    __syncthreads();
    cur ^= 1;
  }
  compute(cur);

#pragma unroll
  for (int fm = 0; fm < FM; ++fm)
#pragma unroll
    for (int fn = 0; fn < 2; ++fn)
#pragma unroll
      for (int j = 0; j < 4; ++j) {
        int row = m0 + wm + fm * 16 + lg * 4 + j;
        int col = n0 + wn + fn * 16 + lc;
        float vv = acc[fm][fn][j] + bias[col];
        size_t idx = (size_t)row * ldo + col;
        if constexpr (EPI == 0) {
          outb[idx] = f2bs(vv);
        } else if constexpr (EPI == 1) {
          outf[idx] = vv + res[idx];
        } else {
          float gx = 0.5f * vv * (1.0f + erff(vv * 0.70710678118f));
          outb[idx] = f2bs(gx);
        }
      }
}

// ------- grouped 5-way projection GEMM: grid (8,32,5), 512 thr dbuf.
__global__ __launch_bounds__(512) void k_gemmG(
    const u16* __restrict__ A0, const u16* __restrict__ A1,
    const u16* __restrict__ A2, const u16* __restrict__ A3,
    const u16* __restrict__ A4, const u16* __restrict__ W0,
    const u16* __restrict__ W1, const u16* __restrict__ W2,
    const u16* __restrict__ W3, const u16* __restrict__ W4,
    const float* __restrict__ b0, const float* __restrict__ b1,
    const float* __restrict__ b2, const float* __restrict__ b3,
    const float* __restrict__ b4, u16* __restrict__ qk1,
    u16* __restrict__ vt1, u16* __restrict__ qk2, u16* __restrict__ vt2) {
  constexpr int BM = 128, BN = 128, BK = 64, K = D_;
  __shared__ __align__(128) char smem[2][(BM + BN) * BK * 2];
  const int z = blockIdx.z;
  const u16* A = z == 0 ? A0 : z == 1 ? A1 : z == 2 ? A2 : z == 3 ? A3 : A4;
  const u16* Bt = z == 0 ? W0 : z == 1 ? W1 : z == 2 ? W2 : z == 3 ? W3 : W4;
  const float* bias = z == 0 ? b0 : z == 1 ? b1 : z == 2 ? b2 : z == 3 ? b3 : b4;
  const int t = threadIdx.x;
  const int wave = t >> 6, lane = t & 63, lg = lane >> 4, lc = lane & 15;
  const int nwg = gridDim.x * gridDim.y;
  const int bid = blockIdx.y * gridDim.x + blockIdx.x;
  const int lb = (bid & 7) * (nwg >> 3) + (bid >> 3);
  const int bx = lb % gridDim.x, by = lb / gridDim.x;
  const int m0 = by * BM, n0 = bx * BN;
  const int wm = (wave >> 2) * 64, wn = (wave & 3) * 32;
  f32x4 acc[4][2];
#pragma unroll
  for (int i = 0; i < 4; ++i)
#pragma unroll
    for (int j = 0; j < 2; ++j) acc[i][j] = (f32x4){0.f, 0.f, 0.f, 0.f};
  const char* Ag = (const char*)(A + (size_t)m0 * K);
  const char* Bg = (const char*)(Bt + (size_t)n0 * K);
  const int sr = t >> 3, sp = t & 7;

  auto stage = [&](int bufi, int kt) {
    char* sA = smem[bufi];
    char* sB = smem[bufi] + BM * BK * 2;
#pragma unroll
    for (int rr = 0; rr < 2; ++rr) {
      int row = rr * 64 + sr;
      int c = sp ^ (row & 7);
      async16(sA + (size_t)row * 128 + sp * 16,
              Ag + ((size_t)row * K + kt + c * 8) * 2);
      async16(sB + (size_t)row * 128 + sp * 16,
              Bg + ((size_t)row * K + kt + c * 8) * 2);
    }
  };
  auto compute = [&](int bufi) {
    const char* sA = smem[bufi];
    const char* sB = smem[bufi] + BM * BK * 2;
#pragma unroll
    for (int ks = 0; ks < 2; ++ks) {
      y16x8 af[4], bfr[2];
#pragma unroll
      for (int fm = 0; fm < 4; ++fm) {
        int R = wm + fm * 16 + lc;
        int pc = (ks * 4 + lg) ^ (R & 7);
        af[fm] = *(const y16x8*)(sA + (size_t)R * 128 + pc * 16);
      }
#pragma unroll
      for (int fn = 0; fn < 2; ++fn) {
        int R = wn + fn * 16 + lc;
        int pc = (ks * 4 + lg) ^ (R & 7);
        bfr[fn] = *(const y16x8*)(sB + (size_t)R * 128 + pc * 16);
      }
#pragma unroll
      for (int fm = 0; fm < 4; ++fm)
#pragma unroll
        for (int fn = 0; fn < 2; ++fn)
          acc[fm][fn] = MFMA(af[fm], bfr[fn], acc[fm][fn]);
    }
  };

  stage(0, 0);
  __syncthreads();
  int cur = 0;
  for (int kt = BK; kt < K; kt += BK) {
    stage(cur ^ 1, kt);
    compute(cur);
    __syncthreads();
    cur ^= 1;
  }
  compute(cur);

  const bool isV = (z == 2) || (z == 4);
  if (!isV) {
    u16* outqk = (z == 3) ? qk2 : qk1;
    const int coff = (z == 1 || z == 3) ? D_ : 0;
#pragma unroll
    for (int fm = 0; fm < 4; ++fm)
#pragma unroll
      for (int fn = 0; fn < 2; ++fn)
#pragma unroll
        for (int j = 0; j < 4; ++j) {
          int row = m0 + wm + fm * 16 + lg * 4 + j;
          int col = n0 + wn + fn * 16 + lc;
          outqk[(size_t)row * (2 * D_) + coff + col] =
              f2bs(acc[fm][fn][j] + bias[col]);
        }
  } else {
    u16* outvt = (z == 2) ? vt1 : vt2;
#pragma unroll
    for (int fm = 0; fm < 4; ++fm)
#pragma unroll
      for (int fn = 0; fn < 2; ++fn) {
        int row0 = m0 + wm + fm * 16 + lg * 4;
        int col = n0 + wn + fn * 16 + lc;
        int bb = row0 >> 10, nn = row0 & (N_ - 1);
        int h = col >> 6, dh = col & 63;
        float bcol = bias[col];
        union { u16 u[4]; uint2 v; } pk;
#pragma unroll
        for (int j = 0; j < 4; ++j) pk.u[j] = f2bs(acc[fm][fn][j] + bcol);
        *(uint2*)&outvt[(((size_t)bb * H_ + h) * DH_ + dh) * N_ + nn] = pk.v;
      }
  }
}

// -------- flash attention + piggy-backed weight transpose (blocks >= 512) ----
// attention: swapped-QK 32x32 MFMA, in-register softmax, 128-key tiles,
// T14 reg prefetch, T13 defer-max, T5 setprio. Transpose blocks reuse Ol
// (18432 B) as the [128][72] tile; consumers are downstream kernels.
__global__ __launch_bounds__(256) void k_attn(const u16* __restrict__ q, int qs,
                                              const u16* __restrict__ k, int ks2,
                                              const u16* __restrict__ vt,
                                              u16* __restrict__ out,
                                              const float* __restrict__ Wsrc,
                                              u16* __restrict__ Wdst,
                                              int WK, int WNcols,
                                              int kmask, int kshift) {
  __shared__ __align__(16) u16 Kl[128][64];
  __shared__ __align__(16) u16 Vl[64][128];
  __shared__ __align__(16) u16 Ol[4][32][72];
  const int lb = blockIdx.x;
  const int t = threadIdx.x;
  if (lb >= 512) {
    // ---- weight transpose: 64k x 128n tile, float4 reads ----
    u16 (*tile)[72] = reinterpret_cast<u16(*)[72]>(&Ol[0][0][0]);
    int rem = lb - 512;
    int k0 = (rem & kmask) * 64, n0 = (rem >> kshift) * 128;
    const int l32 = t & 31, rk = t >> 5;
#pragma unroll
    for (int i = 0; i < 8; ++i) {
      int kk = i * 8 + rk;
      float4 v = *(const float4*)(Wsrc + (size_t)(k0 + kk) * WNcols + n0 + l32 * 4);
      tile[l32 * 4 + 0][kk] = f2bs(v.x);
      tile[l32 * 4 + 1][kk] = f2bs(v.y);
      tile[l32 * 4 + 2][kk] = f2bs(v.z);
      tile[l32 * 4 + 3][kk] = f2bs(v.w);
    }
    __syncthreads();
    const int nr = t >> 3, c = t & 7;
#pragma unroll
    for (int p = 0; p < 4; ++p) {
      int n = p * 32 + nr;
      *(s16x8*)(Wdst + (size_t)(n0 + n) * WK + k0 + c * 8) =
          *(const s16x8*)&tile[n][c * 8];
    }
    return;
  }
  const int bh = (lb & 7) | ((lb >> 6) << 3);
  const int qb = (lb >> 3) & 7;
  const int b = bh >> 4, h = bh & 15;
  const int wave = t >> 6, lane = t & 63;
  const int ql = lane & 31, hi = lane >> 5;
  const int q0 = qb * 128 + wave * 32;
  const u16* qp = q + ((size_t)b * N_ + q0) * qs + h * DH_;
  const u16* kp = k + (size_t)b * N_ * ks2 + h * DH_;
  const u16* vp = vt + ((size_t)bh * DH_) * N_;

  y16x8 aq[4];
#pragma unroll
  for (int s = 0; s < 4; ++s)
    aq[s] = *(const y16x8*)(qp + (size_t)ql * qs + s * 16 + hi * 8);

  f32x16 o0 = ZERO16, o1 = ZERO16;
  float m_r = -1e30f, l_r = 0.f;

  const int kr = t >> 3, kc = t & 7;
  const int vr = t >> 4, vc = t & 15;
  s16x8 kreg[4], vreg[4];
#pragma unroll
  for (int rr = 0; rr < 4; ++rr) {
    kreg[rr] = *(const s16x8*)(kp + (size_t)(rr * 32 + kr) * ks2 + kc * 8);
    vreg[rr] = *(const s16x8*)(vp + (size_t)(rr * 16 + vr) * N_ + vc * 8);
  }

  for (int kt = 0; kt < N_; kt += 128) {
    __syncthreads();
#pragma unroll
    for (int rr = 0; rr < 4; ++rr) {
      int krow = rr * 32 + kr;
      *(s16x8*)&Kl[krow][(kc ^ (krow & 7)) * 8] = kreg[rr];
      int vrow = rr * 16 + vr;
      *(s16x8*)&Vl[vrow][(vc ^ (vrow & 15)) * 8] = vreg[rr];
    }
    __syncthreads();
    if (kt + 128 < N_) {
#pragma unroll
      for (int rr = 0; rr < 4; ++rr) {
        kreg[rr] = *(const s16x8*)(kp + (size_t)(kt + 128 + rr * 32 + kr) * ks2 + kc * 8);
        vreg[rr] = *(const s16x8*)(vp + (size_t)(rr * 16 + vr) * N_ + kt + 128 + vc * 8);
      }
    }

#pragma unroll
    for (int sub = 0; sub < 2; ++sub) {
      f32x16 st0 = ZERO16, st1 = ZERO16;
      __builtin_amdgcn_s_setprio(1);
#pragma unroll
      for (int s = 0; s < 4; ++s) {
        int pc0 = ((s * 2 + hi) ^ (ql & 7)) * 8;
        y16x8 ak0 = *(const y16x8*)&Kl[sub * 64 + ql][pc0];
        y16x8 ak1 = *(const y16x8*)&Kl[sub * 64 + 32 + ql][pc0];
        st0 = MFMA32(ak0, aq[s], st0);
        st1 = MFMA32(ak1, aq[s], st1);
      }
      __builtin_amdgcn_s_setprio(0);

      float mx = st0[0];
#pragma unroll
      for (int r = 1; r < 16; ++r) mx = fmaxf(mx, st0[r]);
#pragma unroll
      for (int r = 0; r < 16; ++r) mx = fmaxf(mx, st1[r]);
      mx = fmaxf(mx, __shfl_xor(mx, 32, 64));
      if (!__all(mx - m_r <= 32.f)) {
        float mn = fmaxf(m_r, mx);
        float corr = exp2f((m_r - mn) * CEXP_);
        l_r *= corr;
        o0 = o0 * corr;
        o1 = o1 * corr;
        m_r = mn;
      }
      float ps = 0.f;
#pragma unroll
      for (int r = 0; r < 16; ++r) {
        float e = exp2f((st0[r] - m_r) * CEXP_); st0[r] = e; ps += e;
      }
#pragma unroll
      for (int r = 0; r < 16; ++r) {
        float e = exp2f((st1[r] - m_r) * CEXP_); st1[r] = e; ps += e;
      }
      ps += __shfl_xor(ps, 32, 64);
      l_r += ps;

      __builtin_amdgcn_s_setprio(1);
#pragma unroll
      for (int ks = 0; ks < 4; ++ks) {
        unsigned A0, A1, B0, B1;
        if (ks < 2) {
          const int il = ks * 8;
          A0 = cvtpk(st0[il + 0], st0[il + 1]);
          A1 = cvtpk(st0[il + 2], st0[il + 3]);
          B0 = cvtpk(st0[il + 4], st0[il + 5]);
          B1 = cvtpk(st0[il + 6], st0[il + 7]);
        } else {
          const int il = (ks - 2) * 8;
          A0 = cvtpk(st1[il + 0], st1[il + 1]);
          A1 = cvtpk(st1[il + 2], st1[il + 3]);
          B0 = cvtpk(st1[il + 4], st1[il + 5]);
          B1 = cvtpk(st1[il + 6], st1[il + 7]);
        }
        asm("v_permlane32_swap_b32 %0, %1" : "+v"(A0), "+v"(B0));
        asm("v_permlane32_swap_b32 %0, %1" : "+v"(A1), "+v"(B1));
        union { unsigned w[4]; y16x8 v; } fr;
        fr.w[0] = A0; fr.w[1] = A1; fr.w[2] = B0; fr.w[3] = B1;
        int ch0 = (sub * 8 + ks * 2 + hi) ^ (ql & 15);
        int ch1 = (sub * 8 + ks * 2 + hi) ^ ((32 + ql) & 15);
        y16x8 bv0 = *(const y16x8*)&Vl[ql][ch0 * 8];
        y16x8 bv1 = *(const y16x8*)&Vl[32 + ql][ch1 * 8];
        o0 = MFMA32(bv0, fr.v, o0);
        o1 = MFMA32(bv1, fr.v, o1);
      }
      __builtin_amdgcn_s_setprio(0);
    }
  }

  float rl = 1.f / l_r;
#pragma unroll
  for (int rq = 0; rq < 4; ++rq)
#pragma unroll
    for (int e = 0; e < 4; e += 2) {
      *(unsigned*)&Ol[wave][ql][8 * rq + 4 * hi + e] =
          cvtpk(o0[rq * 4 + e] * rl, o0[rq * 4 + e + 1] * rl);
      *(unsigned*)&Ol[wave][ql][32 + 8 * rq + 4 * hi + e] =
          cvtpk(o1[rq * 4 + e] * rl, o1[rq * 4 + e + 1] * rl);
    }
#pragma unroll
  for (int pp = 0; pp < 4; ++pp) {
    int row = pp * 8 + (lane >> 3);
    s16x8 vv = *(const s16x8*)&Ol[wave][row][(lane & 7) * 8];
    *(s16x8*)(out + ((size_t)b * N_ + q0 + row) * D_ + h * DH_ + (lane & 7) * 8) = vv;
  }
}

extern "C" void kernel_launch(void* const* d_in, const int* in_sizes, int n_in,
                              void* d_out, int out_size, void* d_ws, size_t ws_size,
                              hipStream_t stream) {
  const float* tokens_enc = (const float*)d_in[0];
  const float* tokens_dec = (const float*)d_in[1];
  const float* PE_enc = (const float*)d_in[2];
  const float* PE_dec = (const float*)d_in[3];
  const float* sa_Wq = (const float*)d_in[4];  const float* sa_bq = (const float*)d_in[5];
  const float* sa_Wk = (const float*)d_in[6];  const float* sa_bk = (const float*)d_in[7];
  const float* sa_Wv = (const float*)d_in[8];  const float* sa_bv = (const float*)d_in[9];
  const float* sa_Wp = (const float*)d_in[10]; const float* sa_bp = (const float*)d_in[11];
  const float* ca_Wq = (const float*)d_in[12]; const float* ca_bq = (const float*)d_in[13];
  const float* ca_Wk = (const float*)d_in[14]; const float* ca_bk = (const float*)d_in[15];
  const float* ca_Wv = (const float*)d_in[16]; const float* ca_bv = (const float*)d_in[17];
  const float* ca_Wp = (const float*)d_in[18]; const float* ca_bp = (const float*)d_in[19];
  const float* mlp_W1 = (const float*)d_in[20]; const float* mlp_b1 = (const float*)d_in[21];
  const float* mlp_W2 = (const float*)d_in[22]; const float* mlp_b2 = (const float*)d_in[23];
  const float* ln1_g = (const float*)d_in[24]; const float* ln1_b = (const float*)d_in[25];
  const float* ln2_g = (const float*)d_in[26]; const float* ln2_b = (const float*)d_in[27];
  const float* ln3_g = (const float*)d_in[28]; const float* ln3_b = (const float*)d_in[29];

  char* wsp = (char*)d_ws;
  size_t off = 0;
  auto alloc = [&](size_t bytes) -> char* {
    char* p = wsp + off;
    off += (bytes + 255) & ~(size_t)255;
    return p;
  };
  u16* w8   = (u16*)alloc((size_t)8 * D_ * D_ * 2);
  u16* w1T  = (u16*)alloc((size_t)DM_ * D_ * 2);
  u16* w2T  = (u16*)alloc((size_t)D_ * DM_ * 2);
  u16* encpe = (u16*)alloc((size_t)NT_ * D_ * 2);
  u16* encv  = (u16*)alloc((size_t)NT_ * D_ * 2);
  u16* x2b = (u16*)alloc((size_t)NT_ * D_ * 2);
  u16* qkb = (u16*)alloc((size_t)NT_ * D_ * 2);
  u16* qkm = (u16*)alloc((size_t)NT_ * 2 * D_ * 2);
  u16* qkm2 = (u16*)alloc((size_t)NT_ * 2 * D_ * 2);
  u16* vtb = (u16*)alloc((size_t)NT_ * D_ * 2);
  u16* vtb2 = (u16*)alloc((size_t)NT_ * D_ * 2);
  u16* attb = (u16*)alloc((size_t)NT_ * D_ * 2);
  float* dec1 = (float*)alloc((size_t)NT_ * D_ * 4);
  float* dec2 = (float*)alloc((size_t)NT_ * D_ * 4);
  u16* hb = (u16*)alloc((size_t)NT_ * DM_ * 2);

  const size_t DD = (size_t)D_ * D_;
  u16* wqT  = w8;
  u16* wkT  = w8 + 1 * DD;
  u16* wvT  = w8 + 2 * DD;
  u16* wpT  = w8 + 3 * DD;
  u16* cwqT = w8 + 4 * DD;
  u16* cwkT = w8 + 5 * DD;
  u16* cwvT = w8 + 6 * DD;
  u16* cwpT = w8 + 7 * DD;

  // ---- prep (8xDxD transposes + encprep + ln1) ----
  k_prep<<<dim3(9216), 256, 0, stream>>>(sa_Wq, sa_Wk, sa_Wv, sa_Wp,
                                         ca_Wq, ca_Wk, ca_Wv, ca_Wp, w8,
                                         tokens_enc, PE_enc, encpe, encv,
                                         tokens_dec, ln1_g, ln1_b, PE_dec,
                                         x2b, qkb);

  // ---- self-attention (+ CA K/V precompute); SA-attn carries W1 transpose --
  k_gemmG<<<dim3(8, 32, 5), 512, 0, stream>>>(
      qkb, qkb, x2b, encpe, encv, wqT, wkT, wvT, cwkT, cwvT,
      sa_bq, sa_bk, sa_bv, ca_bk, ca_bv, qkm, vtb, qkm2, vtb2);
  k_attn<<<dim3(1024), 256, 0, stream>>>(qkm, 2 * D_, qkm + D_, 2 * D_, vtb, attb,
                                         mlp_W1, w1T, D_, DM_, 15, 4);
  k_gemm<1, 64><<<dim3(8, 64), 512, 0, stream>>>(attb, wpT, sa_bp, tokens_dec,
                                                 dec1, nullptr, NT_, D_, D_, D_);

  // ---- cross-attention; CA-attn carries W2 transpose ----
  k_ln<<<dim3(NT_), 256, 0, stream>>>(dec1, ln2_g, ln2_b, PE_dec, x2b, qkb);
  k_gemm<0, 64><<<dim3(8, 64), 512, 0, stream>>>(qkb, cwqT, ca_bq, nullptr,
                                                 nullptr, qkm2, NT_, D_, D_, 2 * D_);
  k_attn<<<dim3(1024), 256, 0, stream>>>(qkm2, 2 * D_, qkm2 + D_, 2 * D_, vtb2, attb,
                                         mlp_W2, w2T, DM_, D_, 63, 6);
  k_gemm<1, 64><<<dim3(8, 64), 512, 0, stream>>>(attb, cwpT, ca_bp, dec1,
                                                 dec2, nullptr, NT_, D_, D_, D_);

  // ---- feed-forward ----
  k_ln<<<dim3(NT_), 256, 0, stream>>>(dec2, ln3_g, ln3_b, nullptr, x2b, nullptr);
  k_gemm<2, 128><<<dim3(32, 32), 512, 0, stream>>>(x2b, w1T, mlp_b1, nullptr,
                                                   nullptr, hb, NT_, DM_, D_, DM_);
  k_gemm<1, 64><<<dim3(8, 64), 512, 0, stream>>>(hb, w2T, mlp_b2, dec2,
                                                 (float*)d_out, nullptr, NT_, D_, DM_, D_);
}